// Round 5
// baseline (216.459 us; speedup 1.0000x reference)
//
#include <hip/hip_runtime.h>
#include <hip/hip_bf16.h>

// CRF log-likelihood, MI355X. SEQ=512, B=1024, T=48.
// One wave = 16 batch chains via MFMA: q[16x48] = p[16x48] @ E[48x48] per step
// (6 x mfma_f32_16x16x32_bf16). Unnormalized scale w/ renorm every 8 steps.
// Emissions double-buffered in LDS via global_load_lds; numerator fused.

constexpr int SEQ = 512, BN = 1024, TTAGS = 48;
constexpr int G = 16, CH = 8, NCH = SEQ / CH;

typedef float f32x4 __attribute__((ext_vector_type(4)));
typedef short s16x8 __attribute__((ext_vector_type(8)));
typedef int   s32x4 __attribute__((ext_vector_type(4)));
typedef int   s32x2 __attribute__((ext_vector_type(2)));
typedef unsigned short u16;

#define LOG2E 1.44269504088896340736f
#define LN2   0.69314718055994530942f

__device__ __forceinline__ float fexp2(float x){ return __builtin_amdgcn_exp2f(x); }
__device__ __forceinline__ float flog2(float x){ return __builtin_amdgcn_logf(x); }
__device__ __forceinline__ u16 f2bf(float f){
    __hip_bfloat16 h = __float2bfloat16(f);
    return __builtin_bit_cast(u16, h);
}
__device__ __forceinline__ f32x4 MFMA(s32x4 a, s32x4 b, f32x4 c){
    return __builtin_amdgcn_mfma_f32_16x16x32_bf16(
        __builtin_bit_cast(s16x8, a), __builtin_bit_cast(s16x8, b), c, 0, 0, 0);
}

__global__ __launch_bounds__(64, 1) void crf_fwd(
    const float* __restrict__ emis, const int* __restrict__ tags,
    const int* __restrict__ mask, const float* __restrict__ start_t,
    const float* __restrict__ end_t, const float* __restrict__ trans,
    float* __restrict__ wsn, float* __restrict__ wsd)
{
    __shared__ float ltr[TTAGS * TTAGS];          // 9216 B
    __shared__ float ebuf[2][CH * 768];           // 2 x 24576 B
    __shared__ __align__(16) u16 Pb[16 * 76];     // 2432 B, row stride 76 u16 (152B)
    __shared__ float stb[48], enb[48];

    const int l  = threadIdx.x;
    const int bl = l & 15;
    const int g  = l >> 4;
    const int b0 = blockIdx.x * G;

    // ---- staging lambda: one 8-step chunk of emissions -> LDS (async) ----
    auto STAGE = [&](int c2, int buf){
        const char* gb = (const char*)emis + (size_t)(c2 * CH) * 196608 + (size_t)b0 * 192;
#pragma unroll
        for (int tt = 0; tt < CH; ++tt)
#pragma unroll
            for (int k = 0; k < 3; ++k)
                __builtin_amdgcn_global_load_lds(
                    (const __attribute__((address_space(1))) void*)(gb + (size_t)tt * 196608 + k * 1024 + l * 16),
                    (__attribute__((address_space(3))) void*)(&ebuf[buf][tt * 768 + k * 256]),
                    16, 0, 0);
    };

    // ---- prologue: stage chunk 0; small tables; frags ----
    STAGE(0, 0);
    int tg0c = tags[(0 * CH +     (l >> 4)) * BN + b0 + bl];
    int tg1c = tags[(0 * CH + 4 + (l >> 4)) * BN + b0 + bl];
    int mk0c = mask[(0 * CH +     (l >> 4)) * BN + b0 + bl];
    int mk1c = mask[(0 * CH + 4 + (l >> 4)) * BN + b0 + bl];

    for (int i = l; i < TTAGS * TTAGS; i += 64) ltr[i] = trans[i];
    if (l < 48) { stb[l] = start_t[l]; enb[l] = end_t[l]; }
    for (int i = l; i < 16 * 76 / 2; i += 64) ((unsigned*)Pb)[i] = 0u;

    // E = exp(trans) as B-fragments: B[k=i][col=j], lane: i = kt*32 + g*8 + e, j = n*16 + bl
    s32x4 Bf0[3], Bf1[3], BeF0, BeF1;
#pragma unroll
    for (int n = 0; n < 3; ++n){
#pragma unroll
        for (int kt = 0; kt < 2; ++kt){
            u16 tmp[8];
#pragma unroll
            for (int e = 0; e < 8; ++e){
                int i = kt * 32 + g * 8 + e;
                int j = n * 16 + bl;
                float x = 0.0f;
                if (i < 48) x = fexp2(ltr[i * 48 + j] * LOG2E);
                tmp[e] = f2bf(x);
            }
            s32x4 fr;
#pragma unroll
            for (int d = 0; d < 4; ++d)
                fr[d] = (int)((unsigned)tmp[2*d] | ((unsigned)tmp[2*d+1] << 16));
            if (kt == 0) Bf0[n] = fr; else Bf1[n] = fr;
        }
    }
    // Bend: B[k=j][any col] = exp(end[j])  (all cols identical)
#pragma unroll
    for (int kt = 0; kt < 2; ++kt){
        u16 tmp[8];
#pragma unroll
        for (int e = 0; e < 8; ++e){
            int jj = kt * 32 + g * 8 + e;
            float x = 0.0f;
            if (jj < 48) x = fexp2(enb[jj] * LOG2E);
            tmp[e] = f2bf(x);
        }
        s32x4 fr;
#pragma unroll
        for (int d = 0; d < 4; ++d)
            fr[d] = (int)((unsigned)tmp[2*d] | ((unsigned)tmp[2*d+1] << 16));
        if (kt == 0) BeF0 = fr; else BeF1 = fr;
    }

    asm volatile("s_waitcnt vmcnt(0) lgkmcnt(0)" ::: "memory");
    __builtin_amdgcn_sched_barrier(0);

    // ---- init (tau = 0): r0 = exp(st + e0) * 2^-6, write through P-LDS, read frags ----
    s32x4 pA0, pA1;
    float la[4];
#pragma unroll
    for (int r = 0; r < 4; ++r){
        la[r] = 6.0f;
#pragma unroll
        for (int n = 0; n < 3; ++n){
            float ev = ebuf[0][g * 192 + bl + r * 48 + n * 16];
            float sv = stb[bl + 16 * n];
            float rv = fexp2(fmaf(sv + ev, LOG2E, -6.0f));
            Pb[g * 304 + r * 76 + bl + 16 * n] = f2bf(rv);
        }
    }
    asm volatile("s_waitcnt lgkmcnt(0)" ::: "memory");
    __builtin_amdgcn_sched_barrier(0);
    {
        const u16* pr = &Pb[bl * 76 + g * 8];
        s32x2 a00 = *(const s32x2*)(pr);
        s32x2 a01 = *(const s32x2*)(pr + 4);
        s32x2 a10 = *(const s32x2*)(pr + 32);
        s32x2 a11 = *(const s32x2*)(pr + 36);
        pA0 = (s32x4){a00[0], a00[1], a01[0], a01[1]};
        pA1 = (s32x4){a10[0], a10[1], a11[0], a11[1]};
    }
    // numerator init
    float numacc; int lasttag, tagprev;
    {
        int idx0 = bl * 4;
        int tag0v = __builtin_amdgcn_ds_bpermute(idx0, tg0c);
        numacc = stb[tag0v] + ebuf[0][bl * 48 + tag0v];
        lasttag = tag0v; tagprev = tag0v;
    }

    STAGE(1, 1);
    int tg0n = tags[(1 * CH +     (l >> 4)) * BN + b0 + bl];
    int tg1n = tags[(1 * CH + 4 + (l >> 4)) * BN + b0 + bl];
    int mk0n = mask[(1 * CH +     (l >> 4)) * BN + b0 + bl];
    int mk1n = mask[(1 * CH + 4 + (l >> 4)) * BN + b0 + bl];

    int cur = 0;
    const float* ebcur = ebuf[0];

    // ---- one forward step ----
    auto STEP = [&](int tt, int renorm){
        const float* ebp = ebcur + tt * 768;
        // raw emissions for this step (C-layout slots)
        float em[4][3];
#pragma unroll
        for (int r = 0; r < 4; ++r)
#pragma unroll
            for (int n = 0; n < 3; ++n)
                em[r][n] = ebp[g * 192 + bl + r * 48 + n * 16];
        // q = p @ E
        f32x4 qn[3];
#pragma unroll
        for (int n = 0; n < 3; ++n){
            qn[n] = MFMA(pA0, Bf0[n], (f32x4){0.f, 0.f, 0.f, 0.f});
            qn[n] = MFMA(pA1, Bf1[n], qn[n]);
        }
        // tags/mask for this step
        int idx  = ((tt & 3) * 16 + bl) * 4;
        int tagv = __builtin_amdgcn_ds_bpermute(idx, (tt < 4) ? tg0c : tg1c);
        int mvec = __builtin_amdgcn_ds_bpermute(idx, (tt < 4) ? mk0c : mk1c);
        unsigned mword = (unsigned)__ballot(mvec != 0) & 0xFFFFu;
        // emul = exp(e) * 2^-6
#pragma unroll
        for (int r = 0; r < 4; ++r)
#pragma unroll
            for (int n = 0; n < 3; ++n)
                em[r][n] = fexp2(fmaf(em[r][n], LOG2E, -6.0f));
        // renorm factors (once per chunk)
        float rcp4[4], l2q0[4];
        if (renorm){
#pragma unroll
            for (int r = 0; r < 4; ++r){
                float q0 = __int_as_float(__builtin_amdgcn_ds_swizzle(__float_as_int(qn[0][r]), 0x10));
                rcp4[r] = __builtin_amdgcn_rcpf(q0);
                l2q0[r] = flog2(q0);
            }
        }
        // r-values -> bf16 -> P-LDS; Z bookkeeping
#pragma unroll
        for (int r = 0; r < 4; ++r){
            float mb = (float)((mword >> (4 * g + r)) & 1u);
            la[r] = fmaf(mb, renorm ? (6.0f + l2q0[r]) : 6.0f, la[r]);
#pragma unroll
            for (int n = 0; n < 3; ++n){
                float rv = qn[n][r] * em[r][n];
                if (renorm) rv *= rcp4[r];
                Pb[g * 304 + r * 76 + bl + 16 * n] = f2bf(rv);
            }
        }
        asm volatile("s_waitcnt lgkmcnt(0)" ::: "memory");
        __builtin_amdgcn_sched_barrier(0);
        // read new A-frags (transpose via LDS), masked select per batch (= bl)
        const u16* pr = &Pb[bl * 76 + g * 8];
        s32x2 a00 = *(const s32x2*)(pr);
        s32x2 a01 = *(const s32x2*)(pr + 4);
        s32x2 a10 = *(const s32x2*)(pr + 32);
        s32x2 a11 = *(const s32x2*)(pr + 36);
        s32x4 nf0 = (s32x4){a00[0], a00[1], a01[0], a01[1]};
        s32x4 nf1 = (s32x4){a10[0], a10[1], a11[0], a11[1]};
        bool mv = (mvec != 0);
        pA0 = mv ? nf0 : pA0;
        pA1 = mv ? nf1 : pA1;
        // numerator gathers
        float eg  = ebp[bl * 48 + tagv];
        float trg = ltr[tagprev * 48 + tagv];
        numacc = numacc + (mv ? (eg + trg) : 0.0f);
        lasttag = mv ? tagv : lasttag;
        tagprev = tagv;
    };

    // ---- main loop over 64 chunks ----
    for (int c = 0; c < NCH; ++c){
        if (c > 0) STEP(0, 1);
#pragma unroll
        for (int tt = 1; tt < CH; ++tt) STEP(tt, 0);
        // chunk boundary: drain staged loads (only vm wait per 8 steps)
        asm volatile("s_waitcnt vmcnt(0) lgkmcnt(0)" ::: "memory");
        __builtin_amdgcn_sched_barrier(0);
        cur ^= 1;
        ebcur = ebuf[cur];
        tg0c = tg0n; tg1c = tg1n; mk0c = mk0n; mk1c = mk1n;
        if (c + 2 < NCH){
            STAGE(c + 2, cur ^ 1);
            tg0n = tags[((c + 2) * CH +     (l >> 4)) * BN + b0 + bl];
            tg1n = tags[((c + 2) * CH + 4 + (l >> 4)) * BN + b0 + bl];
            mk0n = mask[((c + 2) * CH +     (l >> 4)) * BN + b0 + bl];
            mk1n = mask[((c + 2) * CH + 4 + (l >> 4)) * BN + b0 + bl];
        }
    }

    // ---- epilogue: den = ln(sum_j r_j * exp(end_j)) + Z ----
    f32x4 qe = MFMA(pA0, BeF0, (f32x4){0.f, 0.f, 0.f, 0.f});
    qe = MFMA(pA1, BeF1, qe);
#pragma unroll
    for (int r = 0; r < 4; ++r){
        float den = (flog2(qe[r]) + la[r]) * LN2;
        if (bl == 0) wsd[b0 + 4 * g + r] = den;
    }
    if (l < 16){
        numacc += enb[lasttag];
        wsn[b0 + bl] = numacc;
    }
}

__global__ __launch_bounds__(256) void reduce_mean(
    const float* __restrict__ wsn, const float* __restrict__ wsd,
    float* __restrict__ out)
{
    const int tid = threadIdx.x;
    float v = 0.f;
#pragma unroll
    for (int k = 0; k < 4; ++k)
        v += wsn[tid + 256 * k] - wsd[tid + 256 * k];
#pragma unroll
    for (int d = 1; d < 64; d <<= 1)
        v += __shfl_xor(v, d, 64);
    __shared__ float acc[4];
    if ((tid & 63) == 0) acc[tid >> 6] = v;
    __syncthreads();
    if (tid == 0) out[0] = (acc[0] + acc[1] + acc[2] + acc[3]) * (1.f / 1024.f);
}

extern "C" void kernel_launch(void* const* d_in, const int* in_sizes, int n_in,
                              void* d_out, int out_size, void* d_ws, size_t ws_size,
                              hipStream_t stream)
{
    const float* emis    = (const float*)d_in[0];
    const int*   tags    = (const int*)d_in[1];
    const int*   mask    = (const int*)d_in[2];
    const float* start_t = (const float*)d_in[3];
    const float* end_t   = (const float*)d_in[4];
    const float* trans   = (const float*)d_in[5];
    float* wsn = (float*)d_ws;
    float* wsd = wsn + BN;
    float* out = (float*)d_out;

    crf_fwd<<<dim3(BN / G), dim3(64), 0, stream>>>(emis, tags, mask, start_t, end_t, trans, wsn, wsd);
    reduce_mean<<<dim3(1), dim3(256), 0, stream>>>(wsn, wsd, out);
}

// Round 6
// 200.075 us; speedup vs baseline: 1.0819x; 1.0819x over previous
//
#include <hip/hip_runtime.h>

// CRF log-likelihood, MI355X. SEQ=512, B=1024, T=48.
// One wave (64-thread block) per batch chain, lane = tag.
// Linear-domain recurrence: r <- (r @ E) * exp(e)*2^-6, E=exp(trans) pinned in
// 48 VGPRs. No exp/log/readfirstlane on the serial chain; emul precomputed per
// 8-step group; renorm via exact exponent extraction every 8 steps; integer
// log2 bookkeeping. Emissions double-buffered in LDS via global_load_lds.

constexpr int SEQ = 512, BN = 1024, TT = 48;
constexpr int CH = 64, NCH = SEQ / CH;
#define LOG2E 1.44269504088896340736f
#define LN2   0.69314718055994530942f

__device__ __forceinline__ float fexp2(float x) { return __builtin_amdgcn_exp2f(x); }
__device__ __forceinline__ float flog2(float x) { return __builtin_amdgcn_logf(x); }
__device__ __forceinline__ float rlane(float v, int i) {
    return __int_as_float(__builtin_amdgcn_readlane(__float_as_int(v), i));
}

__global__ __launch_bounds__(64, 1) void crf_fwd(
    const float* __restrict__ emis, const int* __restrict__ tags,
    const int* __restrict__ mask, const float* __restrict__ start_t,
    const float* __restrict__ end_t, const float* __restrict__ trans,
    float* __restrict__ ws)
{
    __shared__ float ltr[TT * TT];
    __shared__ __align__(16) float ebuf[2][CH * TT];  // 2 x 12 KB

    const int lane = threadIdx.x;
    const int b = blockIdx.x;

    const bool jv = (lane < TT);
    const int jc = jv ? lane : (TT - 1);

    // per-lane byte offsets for the 12 staging instrs (16B/lane each)
    int offs[12];
#pragma unroll
    for (int k = 0; k < 12; ++k) {
        const int g = k * 64 + lane;
        const int r = g / 12, j4 = g % 12;
        offs[k] = r * (BN * TT * 4) + j4 * 16;
    }

#define STAGE_CHUNK(tb, buf)                                                   \
    {                                                                          \
        const char* cb = (const char*)emis + ((size_t)(tb) * BN + b) * (TT * 4); \
        _Pragma("unroll")                                                      \
        for (int k = 0; k < 12; ++k) {                                         \
            __builtin_amdgcn_global_load_lds(                                  \
                (const __attribute__((address_space(1))) void*)(cb + offs[k]), \
                (__attribute__((address_space(3))) void*)(&ebuf[buf][k * 256]),\
                16, 0, 0);                                                     \
        }                                                                      \
    }

    // ---- prologue ----
    STAGE_CHUNK(0, 0);
    int tgv = tags[(size_t)lane * BN + b];
    int mkv = mask[(size_t)lane * BN + b];
    const int tag0 = tags[b];

    for (int i = lane; i < TT * TT; i += 64) ltr[i] = trans[i];
    __syncthreads();

    // lane j holds column j of E = exp(transitions); pin into VGPRs
    float E[TT];
#pragma unroll
    for (int i = 0; i < TT; ++i)
        E[i] = fexp2(ltr[i * TT + jc] * LOG2E);
#pragma unroll
    for (int i = 0; i < TT; ++i)
        asm volatile("" : "+v"(E[i]));

    const float st = start_t[jc];
    const float en = end_t[jc];

    asm volatile("s_waitcnt vmcnt(0)" ::: "memory");
    __builtin_amdgcn_sched_barrier(0);

    // init (t=0): r = exp(st + e0) * 2^-6
    const float e00 = ebuf[0][jc];
    float r = jv ? fexp2(fmaf(st + e00, LOG2E, -6.0f)) : 0.0f;
    int la = 6;  // uniform log2 bookkeeping

    float numpart = (lane == tag0) ? (st + e00) : 0.f;
    float numtr = 0.f, numem = 0.f;
    int mcount = 0;
    int carry_tag = tag0;

    STAGE_CHUNK(CH, 1);
    int tgn = tags[((size_t)CH + lane) * BN + b];
    int mkn = mask[((size_t)CH + lane) * BN + b];

    int cur = 0;

    for (int c = 0; c < NCH; ++c) {
        const int tbase = c * CH;
        const float* ebc = ebuf[cur];

        // ---- chunk-parallel numerator + mask word (off the serial chain) ----
        const int tmv = (mkv && (tbase + lane) > 0) ? tgv : -1;
        const unsigned long long vmword = __ballot(tmv >= 0);
        int tprev = __shfl_up(tgv, 1, 64);
        if (lane == 0) tprev = carry_tag;
        if (tmv >= 0) {
            numtr += ltr[tprev * TT + tgv];
            numem += ebc[lane * TT + tgv];
        }
        carry_tag = __builtin_amdgcn_readlane(tgv, 63);
        mcount += __popcll(__ballot(mkv != 0));
        la += 6 * (int)__popcll(vmword);

        // group-0 emission rows for this chunk
        float ev[8], evn[8];
#pragma unroll
        for (int u = 0; u < 8; ++u) ev[u] = ebc[u * TT + jc];

        // ---- 8 groups x 8 serial steps ----
#pragma unroll
        for (int sc = 0; sc < 8; ++sc) {
            // emission multipliers for this group (off the serial chain)
            float emul[8];
#pragma unroll
            for (int u = 0; u < 8; ++u)
                emul[u] = fexp2(fmaf(ev[u], LOG2E, -6.0f));
            // prefetch next group's emission rows
            if (sc < 7) {
#pragma unroll
                for (int u = 0; u < 8; ++u)
                    evn[u] = ebc[((sc + 1) * 8 + u) * TT + jc];
            }
            // renorm: exact power-of-2 scale from lane 0's exponent
            {
                const float r0 = rlane(r, 0);
                const int m = ((__float_as_int(r0) >> 23) & 0xFF) - 127;
                const float scl = __int_as_float((127 - m) << 23);
                r *= scl;
                la += m;
            }
            // 8 serial steps: pure readlane+fmac matvec, gated commit
#pragma unroll
            for (int u = 0; u < 8; ++u) {
                float q0 = 0.f, q1 = 0.f, q2 = 0.f, q3 = 0.f;
#pragma unroll
                for (int i = 0; i < TT; i += 4) {
                    q0 = fmaf(rlane(r, i),     E[i],     q0);
                    q1 = fmaf(rlane(r, i + 1), E[i + 1], q1);
                    q2 = fmaf(rlane(r, i + 2), E[i + 2], q2);
                    q3 = fmaf(rlane(r, i + 3), E[i + 3], q3);
                }
                const float q = (q0 + q1) + (q2 + q3);
                const bool commit = (vmword >> (sc * 8 + u)) & 1ull;
                r = commit ? (q * emul[u]) : r;
            }
#pragma unroll
            for (int u = 0; u < 8; ++u) ev[u] = evn[u];
        }

        // ---- chunk boundary: drain staged loads, swap buffers ----
        asm volatile("s_waitcnt vmcnt(0)" ::: "memory");
        __builtin_amdgcn_sched_barrier(0);
        cur ^= 1;
        tgv = tgn; mkv = mkn;
        if (c + 2 < NCH) {
            STAGE_CHUNK(tbase + 2 * CH, cur ^ 1);
            tgn = tags[((size_t)(tbase + 2 * CH) + lane) * BN + b];
            mkn = mask[((size_t)(tbase + 2 * CH) + lane) * BN + b];
        }
    }

    // numerator: end transition at tags[sum(mask)-1]
    const int last_tag = tags[(size_t)(mcount - 1) * BN + b];  // uniform
    numpart += (lane == last_tag) ? en : 0.f;
    numpart += numtr + numem;

    // denominator: ln( sum_j r_j * exp(end_j) ) + la*ln2
    float v = jv ? (r * fexp2(en * LOG2E)) : 0.0f;
    float se = v;
#pragma unroll
    for (int d = 1; d < 64; d <<= 1)
        se += __shfl_xor(se, d, 64);
    const float den = (flog2(se) + (float)la) * LN2;

    float num = numpart;
#pragma unroll
    for (int d = 1; d < 64; d <<= 1)
        num += __shfl_xor(num, d, 64);

    if (lane == 0) ws[b] = num - den;
#undef STAGE_CHUNK
}

__global__ __launch_bounds__(256) void reduce_mean(
    const float* __restrict__ ws, float* __restrict__ out)
{
    const int tid = threadIdx.x;
    float v = ws[tid] + ws[tid + 256] + ws[tid + 512] + ws[tid + 768];
#pragma unroll
    for (int d = 1; d < 64; d <<= 1)
        v += __shfl_xor(v, d, 64);
    __shared__ float acc[4];
    if ((tid & 63) == 0) acc[tid >> 6] = v;
    __syncthreads();
    if (tid == 0) out[0] = (acc[0] + acc[1] + acc[2] + acc[3]) * (1.f / 1024.f);
}

extern "C" void kernel_launch(void* const* d_in, const int* in_sizes, int n_in,
                              void* d_out, int out_size, void* d_ws, size_t ws_size,
                              hipStream_t stream)
{
    const float* emis    = (const float*)d_in[0];
    const int*   tags    = (const int*)d_in[1];
    const int*   mask    = (const int*)d_in[2];
    const float* start_t = (const float*)d_in[3];
    const float* end_t   = (const float*)d_in[4];
    const float* trans   = (const float*)d_in[5];
    float* ws  = (float*)d_ws;
    float* out = (float*)d_out;

    crf_fwd<<<dim3(BN), dim3(64), 0, stream>>>(emis, tags, mask, start_t, end_t, trans, ws);
    reduce_mean<<<dim3(1), dim3(256), 0, stream>>>(ws, out);
}

// Round 7
// 110.670 us; speedup vs baseline: 1.9559x; 1.8078x over previous
//
#include <hip/hip_runtime.h>

// CRF log-likelihood, MI355X. SEQ=512, B=1024, T=48.
// One wave (64-thread block) per batch chain, lane = tag.
// Linear-domain recurrence: r <- (r @ E) * exp(e)*2^-6, E=exp(trans) pinned in
// 48 VGPRs. No exp/log/readfirstlane on the serial chain. emul precomputed per
// 8-step group; renorm via exact exponent extraction once per group; integer
// log2 bookkeeping. Emissions double-buffered in LDS via global_load_lds.
// CODE SIZE DISCIPLINE: only the 8-step group body is unrolled (~6.5 KB);
// chunk & group loops forced unroll-1 so the body stays I-cache-resident
// (R6 regression root cause: 400 KB fully-unrolled kernel streamed from L2).

constexpr int SEQ = 512, BN = 1024, TT = 48;
constexpr int CH = 64, NCH = SEQ / CH;
#define LOG2E 1.44269504088896340736f
#define LN2   0.69314718055994530942f

__device__ __forceinline__ float fexp2(float x) { return __builtin_amdgcn_exp2f(x); }
__device__ __forceinline__ float flog2(float x) { return __builtin_amdgcn_logf(x); }
__device__ __forceinline__ float rlane(float v, int i) {
    return __int_as_float(__builtin_amdgcn_readlane(__float_as_int(v), i));
}

__global__ __launch_bounds__(64, 1) void crf_fwd(
    const float* __restrict__ emis, const int* __restrict__ tags,
    const int* __restrict__ mask, const float* __restrict__ start_t,
    const float* __restrict__ end_t, const float* __restrict__ trans,
    float* __restrict__ ws)
{
    __shared__ float ltr[TT * TT];
    __shared__ __align__(16) float ebuf[2][CH * TT];  // 2 x 12 KB

    const int lane = threadIdx.x;
    const int b = blockIdx.x;

    const bool jv = (lane < TT);
    const int jc = jv ? lane : (TT - 1);

    // per-lane byte offsets for the 12 staging instrs (16B/lane each)
    int offs[12];
#pragma unroll
    for (int k = 0; k < 12; ++k) {
        const int g = k * 64 + lane;
        const int r = g / 12, j4 = g % 12;
        offs[k] = r * (BN * TT * 4) + j4 * 16;
    }

#define STAGE_CHUNK(tb, buf)                                                   \
    {                                                                          \
        const char* cb = (const char*)emis + ((size_t)(tb) * BN + b) * (TT * 4); \
        _Pragma("unroll")                                                      \
        for (int k = 0; k < 12; ++k) {                                         \
            __builtin_amdgcn_global_load_lds(                                  \
                (const __attribute__((address_space(1))) void*)(cb + offs[k]), \
                (__attribute__((address_space(3))) void*)(&ebuf[buf][k * 256]),\
                16, 0, 0);                                                     \
        }                                                                      \
    }

    // ---- prologue ----
    STAGE_CHUNK(0, 0);
    int tgv = tags[(size_t)lane * BN + b];
    int mkv = mask[(size_t)lane * BN + b];
    const int tag0 = tags[b];

    for (int i = lane; i < TT * TT; i += 64) ltr[i] = trans[i];
    __syncthreads();

    // lane j holds column j of E = exp(transitions); pin into VGPRs
    float E[TT];
#pragma unroll
    for (int i = 0; i < TT; ++i)
        E[i] = fexp2(ltr[i * TT + jc] * LOG2E);
#pragma unroll
    for (int i = 0; i < TT; ++i)
        asm volatile("" : "+v"(E[i]));

    const float st = start_t[jc];
    const float en = end_t[jc];

    asm volatile("s_waitcnt vmcnt(0)" ::: "memory");
    __builtin_amdgcn_sched_barrier(0);

    // init (t=0): r = exp(st + e0) * 2^-6
    const float e00 = ebuf[0][jc];
    float r = jv ? fexp2(fmaf(st + e00, LOG2E, -6.0f)) : 0.0f;
    int la = 6;  // uniform log2 bookkeeping

    float numpart = (lane == tag0) ? (st + e00) : 0.f;
    float numtr = 0.f, numem = 0.f;
    int mcount = 0;
    int carry_tag = tag0;

    STAGE_CHUNK(CH, 1);
    int tgn = tags[((size_t)CH + lane) * BN + b];
    int mkn = mask[((size_t)CH + lane) * BN + b];

    int cur = 0;

#pragma unroll 1
    for (int c = 0; c < NCH; ++c) {
        const int tbase = c * CH;
        const float* ebc = ebuf[cur];

        // ---- chunk-parallel numerator + mask word (off the serial chain) ----
        const int tmv = (mkv && (tbase + lane) > 0) ? tgv : -1;
        const unsigned long long vmword = __ballot(tmv >= 0);
        int tprev = __shfl_up(tgv, 1, 64);
        if (lane == 0) tprev = carry_tag;
        if (tmv >= 0) {
            numtr += ltr[tprev * TT + tgv];
            numem += ebc[lane * TT + tgv];
        }
        carry_tag = __builtin_amdgcn_readlane(tgv, 63);
        mcount += __popcll(__ballot(mkv != 0));
        la += 6 * (int)__popcll(vmword);

        // group-0 emission rows for this chunk
        float ev[8];
#pragma unroll
        for (int u = 0; u < 8; ++u) ev[u] = ebc[u * TT + jc];

        // ---- 8 groups x 8 serial steps (group loop NOT unrolled) ----
#pragma unroll 1
        for (int sc = 0; sc < 8; ++sc) {
            // emission multipliers for this group (off the serial chain)
            float emul[8];
#pragma unroll
            for (int u = 0; u < 8; ++u)
                emul[u] = fexp2(fmaf(ev[u], LOG2E, -6.0f));
            // issue next group's emission loads (WAR on ev, emul extracted)
            if (sc < 7) {
#pragma unroll
                for (int u = 0; u < 8; ++u)
                    ev[u] = ebc[((sc + 1) * 8 + u) * TT + jc];
            }
            // per-group commit bits (uniform)
            const unsigned gm = (unsigned)(vmword >> (sc * 8)) & 0xFFu;
            // renorm: exact power-of-2 scale from lane 0's exponent
            {
                const float r0 = rlane(r, 0);
                const int m = ((__float_as_int(r0) >> 23) & 0xFF) - 127;
                const float scl = __int_as_float((127 - m) << 23);
                r *= scl;
                la += m;
            }
            // 8 serial steps: pure readlane+fmac matvec, gated commit
#pragma unroll
            for (int u = 0; u < 8; ++u) {
                float q0 = 0.f, q1 = 0.f, q2 = 0.f, q3 = 0.f;
#pragma unroll
                for (int i = 0; i < TT; i += 4) {
                    q0 = fmaf(rlane(r, i),     E[i],     q0);
                    q1 = fmaf(rlane(r, i + 1), E[i + 1], q1);
                    q2 = fmaf(rlane(r, i + 2), E[i + 2], q2);
                    q3 = fmaf(rlane(r, i + 3), E[i + 3], q3);
                }
                const float q = (q0 + q1) + (q2 + q3);
                const bool commit = (gm >> u) & 1u;
                r = commit ? (q * emul[u]) : r;
            }
        }

        // ---- chunk boundary: drain staged loads, swap buffers ----
        asm volatile("s_waitcnt vmcnt(0)" ::: "memory");
        __builtin_amdgcn_sched_barrier(0);
        cur ^= 1;
        tgv = tgn; mkv = mkn;
        if (c + 2 < NCH) {
            STAGE_CHUNK(tbase + 2 * CH, cur ^ 1);
            tgn = tags[((size_t)(tbase + 2 * CH) + lane) * BN + b];
            mkn = mask[((size_t)(tbase + 2 * CH) + lane) * BN + b];
        }
    }

    // numerator: end transition at tags[sum(mask)-1]
    const int last_tag = tags[(size_t)(mcount - 1) * BN + b];  // uniform
    numpart += (lane == last_tag) ? en : 0.f;
    numpart += numtr + numem;

    // denominator: ln( sum_j r_j * exp(end_j) ) + la*ln2
    float v = jv ? (r * fexp2(en * LOG2E)) : 0.0f;
    float se = v;
#pragma unroll
    for (int d = 1; d < 64; d <<= 1)
        se += __shfl_xor(se, d, 64);
    const float den = (flog2(se) + (float)la) * LN2;

    float num = numpart;
#pragma unroll
    for (int d = 1; d < 64; d <<= 1)
        num += __shfl_xor(num, d, 64);

    if (lane == 0) ws[b] = num - den;
#undef STAGE_CHUNK
}

__global__ __launch_bounds__(256) void reduce_mean(
    const float* __restrict__ ws, float* __restrict__ out)
{
    const int tid = threadIdx.x;
    float v = ws[tid] + ws[tid + 256] + ws[tid + 512] + ws[tid + 768];
#pragma unroll
    for (int d = 1; d < 64; d <<= 1)
        v += __shfl_xor(v, d, 64);
    __shared__ float acc[4];
    if ((tid & 63) == 0) acc[tid >> 6] = v;
    __syncthreads();
    if (tid == 0) out[0] = (acc[0] + acc[1] + acc[2] + acc[3]) * (1.f / 1024.f);
}

extern "C" void kernel_launch(void* const* d_in, const int* in_sizes, int n_in,
                              void* d_out, int out_size, void* d_ws, size_t ws_size,
                              hipStream_t stream)
{
    const float* emis    = (const float*)d_in[0];
    const int*   tags    = (const int*)d_in[1];
    const int*   mask    = (const int*)d_in[2];
    const float* start_t = (const float*)d_in[3];
    const float* end_t   = (const float*)d_in[4];
    const float* trans   = (const float*)d_in[5];
    float* ws  = (float*)d_ws;
    float* out = (float*)d_out;

    crf_fwd<<<dim3(BN), dim3(64), 0, stream>>>(emis, tags, mask, start_t, end_t, trans, ws);
    reduce_mean<<<dim3(1), dim3(256), 0, stream>>>(ws, out);
}